// Round 1
// baseline (10886.081 us; speedup 1.0000x reference)
//
#include <hip/hip_runtime.h>
#include <hip/hip_bf16.h>

// Problem constants
#define N_PTS_IN   20000
#define CAP0C      540000
#define CAP1C      352000
#define ZD 10
#define YD 200
#define XD 704
#define Z1D 5
#define Y1D 100
#define X1D 352
#define HWOUT (YD*XD)   // 140800

// ---------------------------------------------------------------------------
// f_in = sp_feats @ w_in   (20000x64 @ 64x32)
__global__ __launch_bounds__(256) void gemm_in(const float* __restrict__ sp,
                                               const float* __restrict__ w,
                                               float* __restrict__ fout) {
    int tid = blockIdx.x * 256 + threadIdx.x;
    int row = tid >> 3;
    int c4  = (tid & 7) * 4;
    if (row >= N_PTS_IN) return;
    float4 acc = {0.f, 0.f, 0.f, 0.f};
    const float* sr = sp + (size_t)row * 64;
#pragma unroll
    for (int ci = 0; ci < 64; ci += 4) {
        float4 fv = *(const float4*)(sr + ci);
        const float* wp = w + ci * 32 + c4;
        float4 w0 = *(const float4*)(wp);
        float4 w1 = *(const float4*)(wp + 32);
        float4 w2 = *(const float4*)(wp + 64);
        float4 w3 = *(const float4*)(wp + 96);
        acc.x += fv.x*w0.x + fv.y*w1.x + fv.z*w2.x + fv.w*w3.x;
        acc.y += fv.x*w0.y + fv.y*w1.y + fv.z*w2.y + fv.w*w3.y;
        acc.z += fv.x*w0.z + fv.y*w1.z + fv.z*w2.z + fv.w*w3.z;
        acc.w += fv.x*w0.w + fv.y*w1.w + fv.z*w2.w + fv.w*w3.w;
    }
    *(float4*)(fout + (size_t)row * 32 + c4) = acc;
}

// ---------------------------------------------------------------------------
// Rulebook inversion: nbr[s*27+k] = g  (s unique within each k -> no atomics)
__global__ __launch_bounds__(256) void build_nbr(const int* __restrict__ g,
                                                 const int* __restrict__ s,
                                                 int* __restrict__ nbr,
                                                 int P, int cap) {
    int i = blockIdx.x * 256 + threadIdx.x;
    if (i >= 27 * P) return;
    int k = i / P, p = i - k * P;
    int sv = s[(size_t)k * P + p];
    if (sv >= cap) return;              // dummy pair (scatter target == cap)
    nbr[(size_t)sv * 27 + k] = g[(size_t)k * P + p];
}

// voxel -> sparse-row index (pad coords have z == Zdim, dropped like JAX OOB)
__global__ __launch_bounds__(256) void build_vox(const int* __restrict__ coords,
                                                 int* __restrict__ v2r,
                                                 int cap, int Zdim, int Ydim, int Xdim) {
    int r = blockIdx.x * 256 + threadIdx.x;
    if (r >= cap) return;
    int b = coords[4*r], z = coords[4*r+1], y = coords[4*r+2], x = coords[4*r+3];
    if (z >= Zdim) return;
    v2r[(((size_t)b * Zdim + z) * Ydim + y) * Xdim + x] = r;
}

// ---------------------------------------------------------------------------
// Output-stationary sparse conv + BN + ReLU.
// thread = (row, 4 consecutive couts). W layout [27][CIN][COUT].
template <int CIN, int COUT>
__global__ __launch_bounds__(256) void spconv_out(const float* __restrict__ f,
                                                  const float* __restrict__ W,
                                                  const float* __restrict__ bnp,
                                                  const int* __restrict__ nbr,
                                                  float* __restrict__ fout,
                                                  int ncap) {
    constexpr int CO4 = COUT / 4;
    int tid = blockIdx.x * 256 + threadIdx.x;
    int row = tid / CO4;
    int c4  = (tid % CO4) * 4;
    if (row >= ncap) return;
    float4 acc = {0.f, 0.f, 0.f, 0.f};
    const int* nb = nbr + (size_t)row * 27;
#pragma unroll 1
    for (int k = 0; k < 27; ++k) {
        int gi = nb[k];
        if (gi < 0) continue;
        const float* fr = f + (size_t)gi * CIN;
        const float* wk = W + (size_t)k * CIN * COUT + c4;
#pragma unroll
        for (int ci = 0; ci < CIN; ci += 4) {
            float4 fv = *(const float4*)(fr + ci);
            float4 w0 = *(const float4*)(wk + (ci + 0) * COUT);
            float4 w1 = *(const float4*)(wk + (ci + 1) * COUT);
            float4 w2 = *(const float4*)(wk + (ci + 2) * COUT);
            float4 w3 = *(const float4*)(wk + (ci + 3) * COUT);
            acc.x += fv.x*w0.x + fv.y*w1.x + fv.z*w2.x + fv.w*w3.x;
            acc.y += fv.x*w0.y + fv.y*w1.y + fv.z*w2.y + fv.w*w3.y;
            acc.z += fv.x*w0.z + fv.y*w1.z + fv.z*w2.z + fv.w*w3.z;
            acc.w += fv.x*w0.w + fv.y*w1.w + fv.z*w2.w + fv.w*w3.w;
        }
    }
    // BN (gamma,beta,mean,var rows) + ReLU epilogue
    float4 outv;
    {
        float g0 = bnp[c4+0], g1 = bnp[c4+1], g2 = bnp[c4+2], g3 = bnp[c4+3];
        float b0 = bnp[COUT+c4+0], b1 = bnp[COUT+c4+1], b2 = bnp[COUT+c4+2], b3 = bnp[COUT+c4+3];
        float m0 = bnp[2*COUT+c4+0], m1 = bnp[2*COUT+c4+1], m2 = bnp[2*COUT+c4+2], m3 = bnp[2*COUT+c4+3];
        float v0 = bnp[3*COUT+c4+0], v1 = bnp[3*COUT+c4+1], v2 = bnp[3*COUT+c4+2], v3 = bnp[3*COUT+c4+3];
        float s0 = g0 * rsqrtf(v0 + 1e-5f);
        float s1 = g1 * rsqrtf(v1 + 1e-5f);
        float s2 = g2 * rsqrtf(v2 + 1e-5f);
        float s3 = g3 * rsqrtf(v3 + 1e-5f);
        outv.x = fmaxf((acc.x - m0) * s0 + b0, 0.f);
        outv.y = fmaxf((acc.y - m1) * s1 + b1, 0.f);
        outv.z = fmaxf((acc.z - m2) * s2 + b2, 0.f);
        outv.w = fmaxf((acc.w - m3) * s3 + b3, 0.f);
    }
    *(float4*)(fout + (size_t)row * COUT + c4) = outv;
}

// ---------------------------------------------------------------------------
// ct1_w [320][64][2][2] -> wT [kq=ky*2+kx][320][64]
__global__ __launch_bounds__(256) void transpose_ct1(const float* __restrict__ w,
                                                     float* __restrict__ wT) {
    int i = blockIdx.x * 256 + threadIdx.x;
    if (i >= 320 * 64 * 4) return;
    int kq = i & 3;
    int rest = i >> 2;
    int co = rest & 63;
    int ci = rest >> 6;
    wT[((size_t)kq * 320 + ci) * 64 + co] = w[i];
}

// ---------------------------------------------------------------------------
// Scale-0 head: 1x1 convT (channel matmul over (c,z)) + BN + ReLU + attention.
// block = 256 threads = 4 waves, 16 pixels (one y, 16 consecutive x).
// lane = output channel.
__global__ __launch_bounds__(256) void bev0_att(const float* __restrict__ f0,
                                                const float* __restrict__ w,     // [320][64], ci=c*10+z
                                                const float* __restrict__ bias,
                                                const float* __restrict__ bnp,
                                                const int* __restrict__ v2r,
                                                float* __restrict__ out) {
    __shared__ float tile[64][17];
    int lane = threadIdx.x & 63, wv = threadIdx.x >> 6;
    int y = blockIdx.x / 44, x0 = (blockIdx.x % 44) * 16;
    float scale = bnp[lane] * rsqrtf(bnp[192 + lane] + 1e-5f);
    float shift = (bias[lane] - bnp[128 + lane]) * scale + bnp[64 + lane];
    for (int pi = wv; pi < 16; pi += 4) {
        int x = x0 + pi;
        float xv0 = 0.f, xv1 = 0.f;
#pragma unroll
        for (int b = 0; b < 2; ++b) {
            float acc = 0.f;
            for (int z = 0; z < ZD; ++z) {
                int r = v2r[((b * ZD + z) * YD + y) * XD + x];
                if (r < 0) continue;
                float fval = f0[(size_t)r * 32 + (lane & 31)];
                const float* wz = w + z * 64;
#pragma unroll
                for (int c = 0; c < 32; ++c)
                    acc += __shfl(fval, c) * wz[c * 640 + lane];
            }
            float xb = fmaxf(acc * scale + shift, 0.f);
            if (b == 0) xv0 = xb; else xv1 = xb;
        }
        float s00 = xv0 * xv0, s01 = xv0 * xv1;
#pragma unroll
        for (int o = 32; o > 0; o >>= 1) {
            s00 += __shfl_xor(s00, o);
            s01 += __shfl_xor(s01, o);
        }
        float a0 = s00 * 0.125f, a1 = s01 * 0.125f;   // /sqrt(64)
        float mx = fmaxf(a0, a1);
        float e0 = expf(a0 - mx), e1 = expf(a1 - mx);
        float inv = 1.f / (e0 + e1);
        tile[lane][pi] = (e0 * xv0 + e1 * xv1) * inv;
    }
    __syncthreads();
    int px = threadIdx.x & 15, cb = threadIdx.x >> 4;
#pragma unroll
    for (int it = 0; it < 4; ++it) {
        int ch = cb + it * 16;
        out[(size_t)ch * HWOUT + (size_t)y * XD + x0 + px] = tile[ch][px];
    }
}

// ---------------------------------------------------------------------------
// Scale-1 head: 2x2 stride-2 convT + BN + ReLU + attention.
__global__ __launch_bounds__(256) void bev1_att(const float* __restrict__ f1,
                                                const float* __restrict__ wT,   // [4][320][64], ci=c*5+z
                                                const float* __restrict__ bias,
                                                const float* __restrict__ bnp,
                                                const int* __restrict__ v2r,
                                                float* __restrict__ out) {
    __shared__ float tile[64][17];
    int lane = threadIdx.x & 63, wv = threadIdx.x >> 6;
    int y = blockIdx.x / 44, x0 = (blockIdx.x % 44) * 16;
    int iy = y >> 1, ky = y & 1;
    float scale = bnp[lane] * rsqrtf(bnp[192 + lane] + 1e-5f);
    float shift = (bias[lane] - bnp[128 + lane]) * scale + bnp[64 + lane];
    for (int pi = wv; pi < 16; pi += 4) {
        int x = x0 + pi;
        int jx = x >> 1, kx = x & 1;
        const float* wp = wT + (size_t)(ky * 2 + kx) * 320 * 64;
        float xv0 = 0.f, xv1 = 0.f;
#pragma unroll
        for (int b = 0; b < 2; ++b) {
            float acc = 0.f;
            for (int z = 0; z < Z1D; ++z) {
                int r = v2r[((b * Z1D + z) * Y1D + iy) * X1D + jx];
                if (r < 0) continue;
                float fval = f1[(size_t)r * 64 + lane];
                const float* wz = wp + z * 64;
#pragma unroll
                for (int c = 0; c < 64; ++c)
                    acc += __shfl(fval, c) * wz[c * 320 + lane];
            }
            float xb = fmaxf(acc * scale + shift, 0.f);
            if (b == 0) xv0 = xb; else xv1 = xb;
        }
        float s00 = xv0 * xv0, s01 = xv0 * xv1;
#pragma unroll
        for (int o = 32; o > 0; o >>= 1) {
            s00 += __shfl_xor(s00, o);
            s01 += __shfl_xor(s01, o);
        }
        float a0 = s00 * 0.125f, a1 = s01 * 0.125f;
        float mx = fmaxf(a0, a1);
        float e0 = expf(a0 - mx), e1 = expf(a1 - mx);
        float inv = 1.f / (e0 + e1);
        tile[lane][pi] = (e0 * xv0 + e1 * xv1) * inv;
    }
    __syncthreads();
    int px = threadIdx.x & 15, cb = threadIdx.x >> 4;
#pragma unroll
    for (int it = 0; it < 4; ++it) {
        int ch = cb + it * 16;
        out[(size_t)ch * HWOUT + (size_t)y * XD + x0 + px] = tile[ch][px];
    }
}

// ---------------------------------------------------------------------------
extern "C" void kernel_launch(void* const* d_in, const int* in_sizes, int n_in,
                              void* d_out, int out_size, void* d_ws, size_t ws_size,
                              hipStream_t stream) {
    const float* sp    = (const float*)d_in[0];
    const float* w_in  = (const float*)d_in[1];
    const float* w0    = (const float*)d_in[2];
    const float* bnp0  = (const float*)d_in[3];
    const float* w0a   = (const float*)d_in[4];
    const float* bnp0a = (const float*)d_in[5];
    const float* w0b   = (const float*)d_in[6];
    const float* bnp0b = (const float*)d_in[7];
    const float* w1    = (const float*)d_in[8];
    const float* bnp1  = (const float*)d_in[9];
    const float* w1a   = (const float*)d_in[10];
    const float* bnp1a = (const float*)d_in[11];
    const float* w1b   = (const float*)d_in[12];
    const float* bnp1b = (const float*)d_in[13];
    const float* ct0w  = (const float*)d_in[14];
    const float* ct0b  = (const float*)d_in[15];
    const float* bnt0  = (const float*)d_in[16];
    const float* ct1w  = (const float*)d_in[17];
    const float* ct1b  = (const float*)d_in[18];
    const float* bnt1  = (const float*)d_in[19];
    const int* coords0 = (const int*)d_in[20];
    const int* coords1 = (const int*)d_in[21];
    const int* g0 = (const int*)d_in[22];
    const int* s0 = (const int*)d_in[23];
    const int* ga = (const int*)d_in[24];
    const int* sa = (const int*)d_in[25];
    const int* g1 = (const int*)d_in[26];
    const int* s1 = (const int*)d_in[27];
    const int* gb = (const int*)d_in[28];
    const int* sb = (const int*)d_in[29];
    float* out = (float*)d_out;

    // -------- workspace carve (floats) --------
    // fIn: 20000*32            =    640,000
    // R1 : CAP1*64             = 22,528,000  (fA -> f1B)
    // R2 : CAP1*64             = 22,528,000  (fB -> f1A)
    // nbr: CAP0*27 ints        = 14,580,000  (aliased by v2r0/v2r1/ct1T when dead)
    float* fIn = (float*)d_ws;
    float* R1  = fIn + 640000;
    float* R2  = R1 + 22528000;
    int*   nbr = (int*)(R2 + 22528000);
    int*   v2r0 = nbr;                         // 2*10*200*704 = 2,816,000 ints
    int*   v2r1 = nbr + 2816000;               // 2*5*100*352  =   352,000 ints
    float* ct1T = (float*)(nbr + 2816000 + 352000);  // 81,920 floats

    // 1) input channel lift
    gemm_in<<<(N_PTS_IN * 8 + 255) / 256, 256, 0, stream>>>(sp, w_in, fIn);

    // 2) conv0 (stride-1 spconv, 32->32): fIn -> R1
    hipMemsetAsync(nbr, 0xFF, (size_t)CAP0C * 27 * 4, stream);
    build_nbr<<<(27 * N_PTS_IN + 255) / 256, 256, 0, stream>>>(g0, s0, nbr, N_PTS_IN, CAP0C);
    spconv_out<32, 32><<<((size_t)CAP0C * 8 + 255) / 256, 256, 0, stream>>>(fIn, w0, bnp0, nbr, R1, CAP0C);

    // 3) subm a/b (32->32), shared rulebook: R1 -> R2 -> R1
    hipMemsetAsync(nbr, 0xFF, (size_t)CAP0C * 27 * 4, stream);
    build_nbr<<<(27 * CAP0C + 255) / 256, 256, 0, stream>>>(ga, sa, nbr, CAP0C, CAP0C);
    spconv_out<32, 32><<<((size_t)CAP0C * 8 + 255) / 256, 256, 0, stream>>>(R1, w0a, bnp0a, nbr, R2, CAP0C);
    spconv_out<32, 32><<<((size_t)CAP0C * 8 + 255) / 256, 256, 0, stream>>>(R2, w0b, bnp0b, nbr, R1, CAP0C);

    // 4) BEV head 0 (reads R1) -> out channels [0,64)
    hipMemsetAsync(v2r0, 0xFF, (size_t)2816000 * 4, stream);
    build_vox<<<(CAP0C + 255) / 256, 256, 0, stream>>>(coords0, v2r0, CAP0C, ZD, YD, XD);
    bev0_att<<<YD * 44, 256, 0, stream>>>(R1, ct0w, ct0b, bnt0, v2r0, out);

    // 5) conv1 (stride-2 spconv, 32->64): R1 -> R2
    hipMemsetAsync(nbr, 0xFF, (size_t)CAP1C * 27 * 4, stream);
    build_nbr<<<(27 * CAP0C + 255) / 256, 256, 0, stream>>>(g1, s1, nbr, CAP0C, CAP1C);
    spconv_out<32, 64><<<((size_t)CAP1C * 16 + 255) / 256, 256, 0, stream>>>(R1, w1, bnp1, nbr, R2, CAP1C);

    // 6) subm 1a/1b (64->64), shared rulebook: R2 -> R1 -> R2
    hipMemsetAsync(nbr, 0xFF, (size_t)CAP1C * 27 * 4, stream);
    build_nbr<<<(27 * CAP1C + 255) / 256, 256, 0, stream>>>(gb, sb, nbr, CAP1C, CAP1C);
    spconv_out<64, 64><<<((size_t)CAP1C * 16 + 255) / 256, 256, 0, stream>>>(R2, w1a, bnp1a, nbr, R1, CAP1C);
    spconv_out<64, 64><<<((size_t)CAP1C * 16 + 255) / 256, 256, 0, stream>>>(R1, w1b, bnp1b, nbr, R2, CAP1C);

    // 7) BEV head 1 (reads R2) -> out channels [64,128)
    hipMemsetAsync(v2r1, 0xFF, (size_t)352000 * 4, stream);
    build_vox<<<(CAP1C + 255) / 256, 256, 0, stream>>>(coords1, v2r1, CAP1C, Z1D, Y1D, X1D);
    transpose_ct1<<<320, 256, 0, stream>>>(ct1w, ct1T);
    bev1_att<<<YD * 44, 256, 0, stream>>>(R2, ct1T, ct1b, bnt1, v2r1, out + (size_t)64 * HWOUT);
}

// Round 3
// 4149.785 us; speedup vs baseline: 2.6233x; 2.6233x over previous
//
#include <hip/hip_runtime.h>
#include <hip/hip_bf16.h>

// Problem constants
#define N_PTS_IN   20000
#define CAP0C      540000
#define CAP1C      352000
#define ZD 10
#define YD 200
#define XD 704
#define Z1D 5
#define Y1D 100
#define X1D 352
#define HWOUT (YD*XD)   // 140800

// ---------------------------------------------------------------------------
// f_in = sp_feats @ w_in   (20000x64 @ 64x32)
__global__ __launch_bounds__(256) void gemm_in(const float* __restrict__ sp,
                                               const float* __restrict__ w,
                                               float* __restrict__ fout) {
    int tid = blockIdx.x * 256 + threadIdx.x;
    int row = tid >> 3;
    int c4  = (tid & 7) * 4;
    if (row >= N_PTS_IN) return;
    float4 acc = {0.f, 0.f, 0.f, 0.f};
    const float* sr = sp + (size_t)row * 64;
#pragma unroll
    for (int ci = 0; ci < 64; ci += 4) {
        float4 fv = *(const float4*)(sr + ci);
        const float* wp = w + ci * 32 + c4;
        float4 w0 = *(const float4*)(wp);
        float4 w1 = *(const float4*)(wp + 32);
        float4 w2 = *(const float4*)(wp + 64);
        float4 w3 = *(const float4*)(wp + 96);
        acc.x += fv.x*w0.x + fv.y*w1.x + fv.z*w2.x + fv.w*w3.x;
        acc.y += fv.x*w0.y + fv.y*w1.y + fv.z*w2.y + fv.w*w3.y;
        acc.z += fv.x*w0.z + fv.y*w1.z + fv.z*w2.z + fv.w*w3.z;
        acc.w += fv.x*w0.w + fv.y*w1.w + fv.z*w2.w + fv.w*w3.w;
    }
    *(float4*)(fout + (size_t)row * 32 + c4) = acc;
}

// ---------------------------------------------------------------------------
// Rulebook inversion, TRANSPOSED: nbrT[k*cap + s] = g
// (s unique within each k -> no atomics; default fill is -1 via memset 0xFF)
__global__ __launch_bounds__(256) void build_nbr(const int* __restrict__ g,
                                                 const int* __restrict__ s,
                                                 int* __restrict__ nbrT,
                                                 int P, int cap) {
    int i = blockIdx.x * 256 + threadIdx.x;
    if (i >= 27 * P) return;
    int k = i / P, p = i - k * P;
    int sv = s[(size_t)k * P + p];
    if (sv >= cap) return;              // dummy pair (scatter target == cap)
    nbrT[(size_t)k * cap + sv] = g[(size_t)k * P + p];
}

// voxel -> sparse-row index (pad coords have z == Zdim, dropped like JAX OOB)
__global__ __launch_bounds__(256) void build_vox(const int* __restrict__ coords,
                                                 int* __restrict__ v2r,
                                                 int cap, int Zdim, int Ydim, int Xdim) {
    int r = blockIdx.x * 256 + threadIdx.x;
    if (r >= cap) return;
    int b = coords[4*r], z = coords[4*r+1], y = coords[4*r+2], x = coords[4*r+3];
    if (z >= Zdim) return;
    v2r[(((size_t)b * Zdim + z) * Ydim + y) * Xdim + x] = r;
}

// ---------------------------------------------------------------------------
// Output-stationary sparse conv + BN + ReLU, one thread per OUTPUT ROW.
// All W indices are wave-uniform -> compiler scalarizes W into s_load +
// v_fmac(sgpr). Invalid gather -> input row `zrow` (a zeroed row), branchless.
// NOTE: zrow is the INPUT-side zero row (== input row count), NOT ncap.
template <int CIN, int COUT>
__global__ __launch_bounds__(256) void spconv_rows(const float* __restrict__ f,
                                                   const float* __restrict__ W,
                                                   const float* __restrict__ bnp,
                                                   const int* __restrict__ nbrT,
                                                   float* __restrict__ fout,
                                                   int ncap, int zrow) {
    int row = blockIdx.x * 256 + threadIdx.x;
    if (row >= ncap) return;
    float acc[COUT];
#pragma unroll
    for (int i = 0; i < COUT; ++i) acc[i] = 0.f;

#pragma unroll 1
    for (int k = 0; k < 27; ++k) {
        int gi = nbrT[(size_t)k * ncap + row];          // coalesced
        if (__ballot(gi >= 0) == 0ull) continue;        // wave-uniform skip
        int ri = (gi < 0) ? zrow : gi;                  // zrow = zero row
        const float* fr = f + (size_t)ri * CIN;
        const float* wk = W + (size_t)k * CIN * COUT;
#pragma unroll 2
        for (int c4 = 0; c4 < CIN / 4; ++c4) {
            float4 fv = *(const float4*)(fr + c4 * 4);
            const float* wp = wk + c4 * 4 * COUT;       // wave-uniform
#pragma unroll
            for (int co = 0; co < COUT; ++co)
                acc[co] += fv.x * wp[co]          + fv.y * wp[COUT + co]
                         + fv.z * wp[2*COUT + co] + fv.w * wp[3*COUT + co];
        }
    }

    // BN (gamma,beta,mean,var rows) + ReLU epilogue; bnp reads are uniform.
    float* orow = fout + (size_t)row * COUT;
#pragma unroll
    for (int c4 = 0; c4 < COUT / 4; ++c4) {
        float4 o;
        float g0 = bnp[c4*4+0], g1 = bnp[c4*4+1], g2 = bnp[c4*4+2], g3 = bnp[c4*4+3];
        float b0 = bnp[COUT+c4*4+0], b1 = bnp[COUT+c4*4+1], b2 = bnp[COUT+c4*4+2], b3 = bnp[COUT+c4*4+3];
        float m0 = bnp[2*COUT+c4*4+0], m1 = bnp[2*COUT+c4*4+1], m2 = bnp[2*COUT+c4*4+2], m3 = bnp[2*COUT+c4*4+3];
        float v0 = bnp[3*COUT+c4*4+0], v1 = bnp[3*COUT+c4*4+1], v2 = bnp[3*COUT+c4*4+2], v3 = bnp[3*COUT+c4*4+3];
        o.x = fmaxf((acc[c4*4+0] - m0) * (g0 * rsqrtf(v0 + 1e-5f)) + b0, 0.f);
        o.y = fmaxf((acc[c4*4+1] - m1) * (g1 * rsqrtf(v1 + 1e-5f)) + b1, 0.f);
        o.z = fmaxf((acc[c4*4+2] - m2) * (g2 * rsqrtf(v2 + 1e-5f)) + b2, 0.f);
        o.w = fmaxf((acc[c4*4+3] - m3) * (g3 * rsqrtf(v3 + 1e-5f)) + b3, 0.f);
        *(float4*)(orow + c4 * 4) = o;
    }
}

// ---------------------------------------------------------------------------
// ct1_w [320][64][2][2] -> wT [kq=ky*2+kx][320][64]
__global__ __launch_bounds__(256) void transpose_ct1(const float* __restrict__ w,
                                                     float* __restrict__ wT) {
    int i = blockIdx.x * 256 + threadIdx.x;
    if (i >= 320 * 64 * 4) return;
    int kq = i & 3;
    int rest = i >> 2;
    int co = rest & 63;
    int ci = rest >> 6;
    wT[((size_t)kq * 320 + ci) * 64 + co] = w[i];
}

// ---------------------------------------------------------------------------
// Scale-0 head: 1x1 convT (channel matmul over (c,z)) + BN + ReLU + attention.
__global__ __launch_bounds__(256) void bev0_att(const float* __restrict__ f0,
                                                const float* __restrict__ w,     // [320][64], ci=c*10+z
                                                const float* __restrict__ bias,
                                                const float* __restrict__ bnp,
                                                const int* __restrict__ v2r,
                                                float* __restrict__ out) {
    __shared__ float tile[64][17];
    int lane = threadIdx.x & 63, wv = threadIdx.x >> 6;
    int y = blockIdx.x / 44, x0 = (blockIdx.x % 44) * 16;
    float scale = bnp[lane] * rsqrtf(bnp[192 + lane] + 1e-5f);
    float shift = (bias[lane] - bnp[128 + lane]) * scale + bnp[64 + lane];
    for (int pi = wv; pi < 16; pi += 4) {
        int x = x0 + pi;
        float xv0 = 0.f, xv1 = 0.f;
#pragma unroll
        for (int b = 0; b < 2; ++b) {
            float acc = 0.f;
            for (int z = 0; z < ZD; ++z) {
                int r = v2r[((b * ZD + z) * YD + y) * XD + x];
                if (r < 0) continue;
                float fval = f0[(size_t)r * 32 + (lane & 31)];
                const float* wz = w + z * 64;
#pragma unroll
                for (int c = 0; c < 32; ++c)
                    acc += __shfl(fval, c) * wz[c * 640 + lane];
            }
            float xb = fmaxf(acc * scale + shift, 0.f);
            if (b == 0) xv0 = xb; else xv1 = xb;
        }
        float s00 = xv0 * xv0, s01 = xv0 * xv1;
#pragma unroll
        for (int o = 32; o > 0; o >>= 1) {
            s00 += __shfl_xor(s00, o);
            s01 += __shfl_xor(s01, o);
        }
        float a0 = s00 * 0.125f, a1 = s01 * 0.125f;   // /sqrt(64)
        float mx = fmaxf(a0, a1);
        float e0 = expf(a0 - mx), e1 = expf(a1 - mx);
        float inv = 1.f / (e0 + e1);
        tile[lane][pi] = (e0 * xv0 + e1 * xv1) * inv;
    }
    __syncthreads();
    int px = threadIdx.x & 15, cb = threadIdx.x >> 4;
#pragma unroll
    for (int it = 0; it < 4; ++it) {
        int ch = cb + it * 16;
        out[(size_t)ch * HWOUT + (size_t)y * XD + x0 + px] = tile[ch][px];
    }
}

// ---------------------------------------------------------------------------
// Scale-1 head: 2x2 stride-2 convT + BN + ReLU + attention.
__global__ __launch_bounds__(256) void bev1_att(const float* __restrict__ f1,
                                                const float* __restrict__ wT,   // [4][320][64], ci=c*5+z
                                                const float* __restrict__ bias,
                                                const float* __restrict__ bnp,
                                                const int* __restrict__ v2r,
                                                float* __restrict__ out) {
    __shared__ float tile[64][17];
    int lane = threadIdx.x & 63, wv = threadIdx.x >> 6;
    int y = blockIdx.x / 44, x0 = (blockIdx.x % 44) * 16;
    int iy = y >> 1, ky = y & 1;
    float scale = bnp[lane] * rsqrtf(bnp[192 + lane] + 1e-5f);
    float shift = (bias[lane] - bnp[128 + lane]) * scale + bnp[64 + lane];
    for (int pi = wv; pi < 16; pi += 4) {
        int x = x0 + pi;
        int jx = x >> 1, kx = x & 1;
        const float* wp = wT + (size_t)(ky * 2 + kx) * 320 * 64;
        float xv0 = 0.f, xv1 = 0.f;
#pragma unroll
        for (int b = 0; b < 2; ++b) {
            float acc = 0.f;
            for (int z = 0; z < Z1D; ++z) {
                int r = v2r[((b * Z1D + z) * Y1D + iy) * X1D + jx];
                if (r < 0) continue;
                float fval = f1[(size_t)r * 64 + lane];
                const float* wz = wp + z * 64;
#pragma unroll
                for (int c = 0; c < 64; ++c)
                    acc += __shfl(fval, c) * wz[c * 320 + lane];
            }
            float xb = fmaxf(acc * scale + shift, 0.f);
            if (b == 0) xv0 = xb; else xv1 = xb;
        }
        float s00 = xv0 * xv0, s01 = xv0 * xv1;
#pragma unroll
        for (int o = 32; o > 0; o >>= 1) {
            s00 += __shfl_xor(s00, o);
            s01 += __shfl_xor(s01, o);
        }
        float a0 = s00 * 0.125f, a1 = s01 * 0.125f;
        float mx = fmaxf(a0, a1);
        float e0 = expf(a0 - mx), e1 = expf(a1 - mx);
        float inv = 1.f / (e0 + e1);
        tile[lane][pi] = (e0 * xv0 + e1 * xv1) * inv;
    }
    __syncthreads();
    int px = threadIdx.x & 15, cb = threadIdx.x >> 4;
#pragma unroll
    for (int it = 0; it < 4; ++it) {
        int ch = cb + it * 16;
        out[(size_t)ch * HWOUT + (size_t)y * XD + x0 + px] = tile[ch][px];
    }
}

// ---------------------------------------------------------------------------
extern "C" void kernel_launch(void* const* d_in, const int* in_sizes, int n_in,
                              void* d_out, int out_size, void* d_ws, size_t ws_size,
                              hipStream_t stream) {
    const float* sp    = (const float*)d_in[0];
    const float* w_in  = (const float*)d_in[1];
    const float* w0    = (const float*)d_in[2];
    const float* bnp0  = (const float*)d_in[3];
    const float* w0a   = (const float*)d_in[4];
    const float* bnp0a = (const float*)d_in[5];
    const float* w0b   = (const float*)d_in[6];
    const float* bnp0b = (const float*)d_in[7];
    const float* w1    = (const float*)d_in[8];
    const float* bnp1  = (const float*)d_in[9];
    const float* w1a   = (const float*)d_in[10];
    const float* bnp1a = (const float*)d_in[11];
    const float* w1b   = (const float*)d_in[12];
    const float* bnp1b = (const float*)d_in[13];
    const float* ct0w  = (const float*)d_in[14];
    const float* ct0b  = (const float*)d_in[15];
    const float* bnt0  = (const float*)d_in[16];
    const float* ct1w  = (const float*)d_in[17];
    const float* ct1b  = (const float*)d_in[18];
    const float* bnt1  = (const float*)d_in[19];
    const int* coords0 = (const int*)d_in[20];
    const int* coords1 = (const int*)d_in[21];
    const int* g0 = (const int*)d_in[22];
    const int* s0 = (const int*)d_in[23];
    const int* ga = (const int*)d_in[24];
    const int* sa = (const int*)d_in[25];
    const int* g1 = (const int*)d_in[26];
    const int* s1 = (const int*)d_in[27];
    const int* gb = (const int*)d_in[28];
    const int* sb = (const int*)d_in[29];
    float* out = (float*)d_out;

    // -------- workspace carve (floats) --------
    // fIn: 20000*32 + zero row   =    640,032
    // R1 : CAP1*64 + zero row    = 22,528,064
    // R2 : CAP1*64 + zero row    = 22,528,064
    // nbrT: CAP0*27 ints         = 14,580,000 (aliased by v2r0/v2r1/ct1T when dead)
    float* fIn = (float*)d_ws;
    float* R1  = fIn + 640032;
    float* R2  = R1 + 22528064;
    int*   nbrT = (int*)(R2 + 22528064);
    int*   v2r0 = nbrT;                         // 2*10*200*704 = 2,816,000 ints
    int*   v2r1 = nbrT + 2816000;               // 2*5*100*352  =   352,000 ints
    float* ct1T = (float*)(nbrT + 2816000 + 352000);  // 81,920 floats

    // zero rows (gather target for invalid pairs); ws is poisoned every call.
    // 32-ch zero rows live at row 540000 (offset 17,280,000); 64-ch zero rows
    // at row 352000 (offset 22,528,000). Overwrite windows audited: each zero
    // row survives until its consumer runs.
    hipMemsetAsync(fIn + 20000 * 32, 0, 32 * 4, stream);
    hipMemsetAsync(R1 + (size_t)540000 * 32, 0, 32 * 4, stream);
    hipMemsetAsync(R1 + (size_t)352000 * 64, 0, 64 * 4, stream);
    hipMemsetAsync(R2 + (size_t)540000 * 32, 0, 32 * 4, stream);
    hipMemsetAsync(R2 + (size_t)352000 * 64, 0, 64 * 4, stream);

    // 1) input channel lift
    gemm_in<<<(N_PTS_IN * 8 + 255) / 256, 256, 0, stream>>>(sp, w_in, fIn);

    // 2) conv0 (stride-1 spconv, 32->32): fIn -> R1   [input rows: 20000]
    hipMemsetAsync(nbrT, 0xFF, (size_t)CAP0C * 27 * 4, stream);
    build_nbr<<<(27 * N_PTS_IN + 255) / 256, 256, 0, stream>>>(g0, s0, nbrT, N_PTS_IN, CAP0C);
    spconv_rows<32, 32><<<(CAP0C + 255) / 256, 256, 0, stream>>>(fIn, w0, bnp0, nbrT, R1, CAP0C, 20000);

    // 3) subm a/b (32->32), shared rulebook: R1 -> R2 -> R1  [input rows: 540000]
    hipMemsetAsync(nbrT, 0xFF, (size_t)CAP0C * 27 * 4, stream);
    build_nbr<<<(27 * CAP0C + 255) / 256, 256, 0, stream>>>(ga, sa, nbrT, CAP0C, CAP0C);
    spconv_rows<32, 32><<<(CAP0C + 255) / 256, 256, 0, stream>>>(R1, w0a, bnp0a, nbrT, R2, CAP0C, 540000);
    spconv_rows<32, 32><<<(CAP0C + 255) / 256, 256, 0, stream>>>(R2, w0b, bnp0b, nbrT, R1, CAP0C, 540000);

    // 4) BEV head 0 (reads R1) -> out channels [0,64)
    hipMemsetAsync(v2r0, 0xFF, (size_t)2816000 * 4, stream);
    build_vox<<<(CAP0C + 255) / 256, 256, 0, stream>>>(coords0, v2r0, CAP0C, ZD, YD, XD);
    bev0_att<<<YD * 44, 256, 0, stream>>>(R1, ct0w, ct0b, bnt0, v2r0, out);

    // 5) conv1 (stride-2 spconv, 32->64): R1 -> R2   [input rows: 540000]
    hipMemsetAsync(nbrT, 0xFF, (size_t)CAP1C * 27 * 4, stream);
    build_nbr<<<(27 * CAP0C + 255) / 256, 256, 0, stream>>>(g1, s1, nbrT, CAP0C, CAP1C);
    spconv_rows<32, 64><<<(CAP1C + 255) / 256, 256, 0, stream>>>(R1, w1, bnp1, nbrT, R2, CAP1C, 540000);

    // 6) subm 1a/1b (64->64), shared rulebook: R2 -> R1 -> R2  [input rows: 352000]
    hipMemsetAsync(nbrT, 0xFF, (size_t)CAP1C * 27 * 4, stream);
    build_nbr<<<(27 * CAP1C + 255) / 256, 256, 0, stream>>>(gb, sb, nbrT, CAP1C, CAP1C);
    spconv_rows<64, 64><<<(CAP1C + 255) / 256, 256, 0, stream>>>(R2, w1a, bnp1a, nbrT, R1, CAP1C, 352000);
    spconv_rows<64, 64><<<(CAP1C + 255) / 256, 256, 0, stream>>>(R1, w1b, bnp1b, nbrT, R2, CAP1C, 352000);

    // 7) BEV head 1 (reads R2) -> out channels [64,128)
    hipMemsetAsync(v2r1, 0xFF, (size_t)352000 * 4, stream);
    build_vox<<<(CAP1C + 255) / 256, 256, 0, stream>>>(coords1, v2r1, CAP1C, Z1D, Y1D, X1D);
    transpose_ct1<<<320, 256, 0, stream>>>(ct1w, ct1T);
    bev1_att<<<YD * 44, 256, 0, stream>>>(R2, ct1T, ct1b, bnt1, v2r1, out + (size_t)64 * HWOUT);
}

// Round 4
// 2890.620 us; speedup vs baseline: 3.7660x; 1.4356x over previous
//
#include <hip/hip_runtime.h>
#include <hip/hip_bf16.h>
#include <hip/hip_fp16.h>

// Problem constants
#define N_PTS_IN   20000
#define CAP0C      540000
#define CAP1C      352000
#define ZD 10
#define YD 200
#define XD 704
#define Z1D 5
#define Y1D 100
#define X1D 352
#define HWOUT (YD*XD)   // 140800

typedef _Float16 f16x8 __attribute__((ext_vector_type(8)));
typedef float    f32x4 __attribute__((ext_vector_type(4)));

// ---------------------------------------------------------------------------
// f_in = sp_feats @ w_in   (20000x64 @ 64x32), f16 output rows
__global__ __launch_bounds__(256) void gemm_in(const float* __restrict__ sp,
                                               const float* __restrict__ w,
                                               __half* __restrict__ fout) {
    int tid = blockIdx.x * 256 + threadIdx.x;
    int row = tid >> 3;
    int c4  = (tid & 7) * 4;
    if (row >= N_PTS_IN) return;
    float4 acc = {0.f, 0.f, 0.f, 0.f};
    const float* sr = sp + (size_t)row * 64;
#pragma unroll
    for (int ci = 0; ci < 64; ci += 4) {
        float4 fv = *(const float4*)(sr + ci);
        const float* wp = w + ci * 32 + c4;
        float4 w0 = *(const float4*)(wp);
        float4 w1 = *(const float4*)(wp + 32);
        float4 w2 = *(const float4*)(wp + 64);
        float4 w3 = *(const float4*)(wp + 96);
        acc.x += fv.x*w0.x + fv.y*w1.x + fv.z*w2.x + fv.w*w3.x;
        acc.y += fv.x*w0.y + fv.y*w1.y + fv.z*w2.y + fv.w*w3.y;
        acc.z += fv.x*w0.z + fv.y*w1.z + fv.z*w2.z + fv.w*w3.z;
        acc.w += fv.x*w0.w + fv.y*w1.w + fv.z*w2.w + fv.w*w3.w;
    }
    __half* fo = fout + (size_t)row * 32 + c4;
    fo[0] = __float2half(acc.x);
    fo[1] = __float2half(acc.y);
    fo[2] = __float2half(acc.z);
    fo[3] = __float2half(acc.w);
}

// ---------------------------------------------------------------------------
// Weight convert+transpose: src f32 [27][CIN][COUT] -> dst f16 [27][COUT][CIN]
__global__ __launch_bounds__(256) void cvt_w(const float* __restrict__ src,
                                             __half* __restrict__ dst,
                                             int CIN, int COUT) {
    int i = blockIdx.x * 256 + threadIdx.x;
    if (i >= 27 * CIN * COUT) return;
    int ci = i % CIN;
    int t  = i / CIN;
    int co = t % COUT;
    int k  = t / COUT;
    dst[i] = __float2half(src[((size_t)k * CIN + ci) * COUT + co]);
}

// ---------------------------------------------------------------------------
// Rulebook inversion, TRANSPOSED: nbrT[k*cap + s] = g
__global__ __launch_bounds__(256) void build_nbr(const int* __restrict__ g,
                                                 const int* __restrict__ s,
                                                 int* __restrict__ nbrT,
                                                 int P, int cap) {
    int i = blockIdx.x * 256 + threadIdx.x;
    if (i >= 27 * P) return;
    int k = i / P, p = i - k * P;
    int sv = s[(size_t)k * P + p];
    if (sv >= cap) return;              // dummy pair
    nbrT[(size_t)k * cap + sv] = g[(size_t)k * P + p];
}

// voxel -> sparse-row index (pad coords have z == Zdim, dropped like JAX OOB)
__global__ __launch_bounds__(256) void build_vox(const int* __restrict__ coords,
                                                 int* __restrict__ v2r,
                                                 int cap, int Zdim, int Ydim, int Xdim) {
    int r = blockIdx.x * 256 + threadIdx.x;
    if (r >= cap) return;
    int b = coords[4*r], z = coords[4*r+1], y = coords[4*r+2], x = coords[4*r+3];
    if (z >= Zdim) return;
    v2r[(((size_t)b * Zdim + z) * Ydim + y) * Xdim + x] = r;
}

// ---------------------------------------------------------------------------
// Implicit-GEMM sparse conv via f16 MFMA 16x16x32, + BN + ReLU.
// Block = 256 thr = 4 waves, M-tile 64 rows, N = COUT, K-loop over 27*CIN.
// A staged in padded LDS (invalid gather -> zeros); B (wt [27][COUT][CIN] f16)
// fragments read directly from global (L1/L2-hot).
// Layouts (verified, learn_hip m89/m91/m120): A[m=lane&15][k=quad*8+j],
// B[k=quad*8+j][n=lane&15], C/D: n=lane&15, m=quad*4+reg.
template <int CIN, int COUT>
__global__ __launch_bounds__(256) void spconv_mfma(const __half* __restrict__ f,
                                                   const __half* __restrict__ wt,
                                                   const float* __restrict__ bnp,
                                                   const int* __restrict__ nbrT,
                                                   __half* __restrict__ fout,
                                                   int ncap) {
    constexpr int AST = CIN + 8;                 // LDS A row stride (halves): +16B pad
    constexpr int ABYTES = 64 * AST * 2;
    constexpr int OBYTES = 64 * COUT * 2;
    constexpr int LDSB = (ABYTES > OBYTES) ? ABYTES : OBYTES;
    constexpr int NT = COUT / 16;
    constexpr int KT = CIN / 32;
    __shared__ __align__(16) char smem[LDSB];
    __half* Al = (__half*)smem;

    int tid = threadIdx.x;
    int m0 = blockIdx.x * 64;
    int wv = tid >> 6, lane = tid & 63;
    int quad = lane >> 4, l16 = lane & 15;

    // staging role: 4 threads per row
    int srow = tid >> 2;                 // 0..63
    int schunk = tid & 3;
    int grow = m0 + srow;
    bool rowok = grow < ncap;

    // BN scale/shift per owned column
    float bs[NT], bb[NT];
#pragma unroll
    for (int nt = 0; nt < NT; ++nt) {
        int co = nt * 16 + l16;
        float g = bnp[co], b = bnp[COUT + co];
        float m = bnp[2*COUT + co], v = bnp[3*COUT + co];
        float s = g * rsqrtf(v + 1e-5f);
        bs[nt] = s;
        bb[nt] = b - m * s;
    }

    f32x4 acc[NT] = {};

#pragma unroll 1
    for (int k = 0; k < 27; ++k) {
        int gi = rowok ? nbrT[(size_t)k * ncap + grow] : -1;
        // doubles as the WAR barrier for the LDS A-tile
        if (!__syncthreads_or(gi >= 0)) continue;
        // stage A-tile (zeros for invalid)
#pragma unroll
        for (int it = 0; it < CIN / 32; ++it) {
            int ch = schunk + it * 4;            // 8-half chunks
            uint4 v4 = {0u, 0u, 0u, 0u};
            if (gi >= 0) v4 = *(const uint4*)(f + (size_t)gi * CIN + ch * 8);
            *(uint4*)(Al + srow * AST + ch * 8) = v4;
        }
        __syncthreads();
        // MFMA
        const __half* wk = wt + (size_t)k * COUT * CIN;
#pragma unroll
        for (int kt = 0; kt < KT; ++kt) {
            f16x8 a = *(const f16x8*)(Al + (wv * 16 + l16) * AST + kt * 32 + quad * 8);
#pragma unroll
            for (int nt = 0; nt < NT; ++nt) {
                f16x8 b = *(const f16x8*)(wk + (size_t)(nt * 16 + l16) * CIN + kt * 32 + quad * 8);
                acc[nt] = __builtin_amdgcn_mfma_f32_16x16x32_f16(a, b, acc[nt], 0, 0, 0);
            }
        }
    }

    // epilogue: BN + ReLU -> f16 tile in LDS -> coalesced store
    __syncthreads();
    __half* Ol = (__half*)smem;
#pragma unroll
    for (int nt = 0; nt < NT; ++nt) {
#pragma unroll
        for (int r = 0; r < 4; ++r) {
            int m = wv * 16 + quad * 4 + r;
            float v = fmaxf(acc[nt][r] * bs[nt] + bb[nt], 0.f);
            Ol[m * COUT + nt * 16 + l16] = __float2half(v);
        }
    }
    __syncthreads();
#pragma unroll
    for (int it = 0; it < COUT / 32; ++it) {
        int ch = schunk + it * 4;
        if (rowok)
            *(uint4*)(fout + (size_t)grow * COUT + ch * 8) =
                *(const uint4*)(Ol + srow * COUT + ch * 8);
    }
}

// ---------------------------------------------------------------------------
// ct1_w [320][64][2][2] -> wT [kq=ky*2+kx][320][64]  (f32)
__global__ __launch_bounds__(256) void transpose_ct1(const float* __restrict__ w,
                                                     float* __restrict__ wT) {
    int i = blockIdx.x * 256 + threadIdx.x;
    if (i >= 320 * 64 * 4) return;
    int kq = i & 3;
    int rest = i >> 2;
    int co = rest & 63;
    int ci = rest >> 6;
    wT[((size_t)kq * 320 + ci) * 64 + co] = w[i];
}

// ---------------------------------------------------------------------------
// Scale-0 head: 1x1 convT + BN + ReLU + attention. f16 feature input.
__global__ __launch_bounds__(256) void bev0_att(const __half* __restrict__ f0,
                                                const float* __restrict__ w,     // [320][64], ci=c*10+z
                                                const float* __restrict__ bias,
                                                const float* __restrict__ bnp,
                                                const int* __restrict__ v2r,
                                                float* __restrict__ out) {
    __shared__ float tile[64][17];
    int lane = threadIdx.x & 63, wv = threadIdx.x >> 6;
    int y = blockIdx.x / 44, x0 = (blockIdx.x % 44) * 16;
    float scale = bnp[lane] * rsqrtf(bnp[192 + lane] + 1e-5f);
    float shift = (bias[lane] - bnp[128 + lane]) * scale + bnp[64 + lane];
    for (int pi = wv; pi < 16; pi += 4) {
        int x = x0 + pi;
        float xv0 = 0.f, xv1 = 0.f;
#pragma unroll
        for (int b = 0; b < 2; ++b) {
            float acc = 0.f;
            for (int z = 0; z < ZD; ++z) {
                int r = v2r[((b * ZD + z) * YD + y) * XD + x];
                if (r < 0) continue;
                float fval = __half2float(f0[(size_t)r * 32 + (lane & 31)]);
                const float* wz = w + z * 64;
#pragma unroll
                for (int c = 0; c < 32; ++c)
                    acc += __shfl(fval, c) * wz[c * 640 + lane];
            }
            float xb = fmaxf(acc * scale + shift, 0.f);
            if (b == 0) xv0 = xb; else xv1 = xb;
        }
        float s00 = xv0 * xv0, s01 = xv0 * xv1;
#pragma unroll
        for (int o = 32; o > 0; o >>= 1) {
            s00 += __shfl_xor(s00, o);
            s01 += __shfl_xor(s01, o);
        }
        float a0 = s00 * 0.125f, a1 = s01 * 0.125f;   // /sqrt(64)
        float mx = fmaxf(a0, a1);
        float e0 = expf(a0 - mx), e1 = expf(a1 - mx);
        float inv = 1.f / (e0 + e1);
        tile[lane][pi] = (e0 * xv0 + e1 * xv1) * inv;
    }
    __syncthreads();
    int px = threadIdx.x & 15, cb = threadIdx.x >> 4;
#pragma unroll
    for (int it = 0; it < 4; ++it) {
        int ch = cb + it * 16;
        out[(size_t)ch * HWOUT + (size_t)y * XD + x0 + px] = tile[ch][px];
    }
}

// ---------------------------------------------------------------------------
// Scale-1 head: 2x2 stride-2 convT + BN + ReLU + attention. f16 features.
__global__ __launch_bounds__(256) void bev1_att(const __half* __restrict__ f1,
                                                const float* __restrict__ wT,   // [4][320][64], ci=c*5+z
                                                const float* __restrict__ bias,
                                                const float* __restrict__ bnp,
                                                const int* __restrict__ v2r,
                                                float* __restrict__ out) {
    __shared__ float tile[64][17];
    int lane = threadIdx.x & 63, wv = threadIdx.x >> 6;
    int y = blockIdx.x / 44, x0 = (blockIdx.x % 44) * 16;
    int iy = y >> 1, ky = y & 1;
    float scale = bnp[lane] * rsqrtf(bnp[192 + lane] + 1e-5f);
    float shift = (bias[lane] - bnp[128 + lane]) * scale + bnp[64 + lane];
    for (int pi = wv; pi < 16; pi += 4) {
        int x = x0 + pi;
        int jx = x >> 1, kx = x & 1;
        const float* wp = wT + (size_t)(ky * 2 + kx) * 320 * 64;
        float xv0 = 0.f, xv1 = 0.f;
#pragma unroll
        for (int b = 0; b < 2; ++b) {
            float acc = 0.f;
            for (int z = 0; z < Z1D; ++z) {
                int r = v2r[((b * Z1D + z) * Y1D + iy) * X1D + jx];
                if (r < 0) continue;
                float fval = __half2float(f1[(size_t)r * 64 + lane]);
                const float* wz = wp + z * 64;
#pragma unroll
                for (int c = 0; c < 64; ++c)
                    acc += __shfl(fval, c) * wz[c * 320 + lane];
            }
            float xb = fmaxf(acc * scale + shift, 0.f);
            if (b == 0) xv0 = xb; else xv1 = xb;
        }
        float s00 = xv0 * xv0, s01 = xv0 * xv1;
#pragma unroll
        for (int o = 32; o > 0; o >>= 1) {
            s00 += __shfl_xor(s00, o);
            s01 += __shfl_xor(s01, o);
        }
        float a0 = s00 * 0.125f, a1 = s01 * 0.125f;
        float mx = fmaxf(a0, a1);
        float e0 = expf(a0 - mx), e1 = expf(a1 - mx);
        float inv = 1.f / (e0 + e1);
        tile[lane][pi] = (e0 * xv0 + e1 * xv1) * inv;
    }
    __syncthreads();
    int px = threadIdx.x & 15, cb = threadIdx.x >> 4;
#pragma unroll
    for (int it = 0; it < 4; ++it) {
        int ch = cb + it * 16;
        out[(size_t)ch * HWOUT + (size_t)y * XD + x0 + px] = tile[ch][px];
    }
}

// ---------------------------------------------------------------------------
extern "C" void kernel_launch(void* const* d_in, const int* in_sizes, int n_in,
                              void* d_out, int out_size, void* d_ws, size_t ws_size,
                              hipStream_t stream) {
    const float* sp    = (const float*)d_in[0];
    const float* w_in  = (const float*)d_in[1];
    const float* w0    = (const float*)d_in[2];
    const float* bnp0  = (const float*)d_in[3];
    const float* w0a   = (const float*)d_in[4];
    const float* bnp0a = (const float*)d_in[5];
    const float* w0b   = (const float*)d_in[6];
    const float* bnp0b = (const float*)d_in[7];
    const float* w1    = (const float*)d_in[8];
    const float* bnp1  = (const float*)d_in[9];
    const float* w1a   = (const float*)d_in[10];
    const float* bnp1a = (const float*)d_in[11];
    const float* w1b   = (const float*)d_in[12];
    const float* bnp1b = (const float*)d_in[13];
    const float* ct0w  = (const float*)d_in[14];
    const float* ct0b  = (const float*)d_in[15];
    const float* bnt0  = (const float*)d_in[16];
    const float* ct1w  = (const float*)d_in[17];
    const float* ct1b  = (const float*)d_in[18];
    const float* bnt1  = (const float*)d_in[19];
    const int* coords0 = (const int*)d_in[20];
    const int* coords1 = (const int*)d_in[21];
    const int* g0 = (const int*)d_in[22];
    const int* s0 = (const int*)d_in[23];
    const int* ga = (const int*)d_in[24];
    const int* sa = (const int*)d_in[25];
    const int* g1 = (const int*)d_in[26];
    const int* s1 = (const int*)d_in[27];
    const int* gb = (const int*)d_in[28];
    const int* sb = (const int*)d_in[29];
    float* out = (float*)d_out;

    // -------- workspace carve --------
    // halves: fInH 640,000 | R1h 22,528,000 | R2h 22,528,000 | WT 359,424
    // then ints: nbrT 14,580,000 (aliased by v2r0/v2r1/ct1T when dead)
    __half* fInH = (__half*)d_ws;
    __half* R1h  = fInH + 640000;
    __half* R2h  = R1h + 22528000;
    __half* wt0  = R2h + 22528000;
    __half* wt0a = wt0  + 27648;
    __half* wt0b = wt0a + 27648;
    __half* wt1  = wt0b + 27648;          // [27][64][32]
    __half* wt1a = wt1  + 55296;          // [27][64][64]
    __half* wt1b = wt1a + 110592;
    int*   nbrT = (int*)(wt1b + 110592);
    int*   v2r0 = nbrT;                          // 2,816,000 ints
    int*   v2r1 = nbrT + 2816000;                //   352,000 ints
    float* ct1T = (float*)(nbrT + 2816000 + 352000);  // 81,920 floats

    // 0) weight conversion (f32 -> f16, transposed to [27][COUT][CIN])
    cvt_w<<<(27*32*32 + 255) / 256, 256, 0, stream>>>(w0,  wt0,  32, 32);
    cvt_w<<<(27*32*32 + 255) / 256, 256, 0, stream>>>(w0a, wt0a, 32, 32);
    cvt_w<<<(27*32*32 + 255) / 256, 256, 0, stream>>>(w0b, wt0b, 32, 32);
    cvt_w<<<(27*32*64 + 255) / 256, 256, 0, stream>>>(w1,  wt1,  32, 64);
    cvt_w<<<(27*64*64 + 255) / 256, 256, 0, stream>>>(w1a, wt1a, 64, 64);
    cvt_w<<<(27*64*64 + 255) / 256, 256, 0, stream>>>(w1b, wt1b, 64, 64);

    // 1) input channel lift (f16 rows out)
    gemm_in<<<(N_PTS_IN * 8 + 255) / 256, 256, 0, stream>>>(sp, w_in, fInH);

    // 2) conv0 (stride-1 spconv, 32->32): fInH -> R1h
    hipMemsetAsync(nbrT, 0xFF, (size_t)CAP0C * 27 * 4, stream);
    build_nbr<<<(27 * N_PTS_IN + 255) / 256, 256, 0, stream>>>(g0, s0, nbrT, N_PTS_IN, CAP0C);
    spconv_mfma<32, 32><<<(CAP0C + 63) / 64, 256, 0, stream>>>(fInH, wt0, bnp0, nbrT, R1h, CAP0C);

    // 3) subm a/b (32->32), shared rulebook: R1h -> R2h -> R1h
    hipMemsetAsync(nbrT, 0xFF, (size_t)CAP0C * 27 * 4, stream);
    build_nbr<<<(27 * CAP0C + 255) / 256, 256, 0, stream>>>(ga, sa, nbrT, CAP0C, CAP0C);
    spconv_mfma<32, 32><<<(CAP0C + 63) / 64, 256, 0, stream>>>(R1h, wt0a, bnp0a, nbrT, R2h, CAP0C);
    spconv_mfma<32, 32><<<(CAP0C + 63) / 64, 256, 0, stream>>>(R2h, wt0b, bnp0b, nbrT, R1h, CAP0C);

    // 4) BEV head 0 (reads R1h) -> out channels [0,64)
    hipMemsetAsync(v2r0, 0xFF, (size_t)2816000 * 4, stream);
    build_vox<<<(CAP0C + 255) / 256, 256, 0, stream>>>(coords0, v2r0, CAP0C, ZD, YD, XD);
    bev0_att<<<YD * 44, 256, 0, stream>>>(R1h, ct0w, ct0b, bnt0, v2r0, out);

    // 5) conv1 (stride-2 spconv, 32->64): R1h -> R2h
    hipMemsetAsync(nbrT, 0xFF, (size_t)CAP1C * 27 * 4, stream);
    build_nbr<<<(27 * CAP0C + 255) / 256, 256, 0, stream>>>(g1, s1, nbrT, CAP0C, CAP1C);
    spconv_mfma<32, 64><<<(CAP1C + 63) / 64, 256, 0, stream>>>(R1h, wt1, bnp1, nbrT, R2h, CAP1C);

    // 6) subm 1a/1b (64->64), shared rulebook: R2h -> R1h -> R2h
    hipMemsetAsync(nbrT, 0xFF, (size_t)CAP1C * 27 * 4, stream);
    build_nbr<<<(27 * CAP1C + 255) / 256, 256, 0, stream>>>(gb, sb, nbrT, CAP1C, CAP1C);
    spconv_mfma<64, 64><<<(CAP1C + 63) / 64, 256, 0, stream>>>(R2h, wt1a, bnp1a, nbrT, R1h, CAP1C);
    spconv_mfma<64, 64><<<(CAP1C + 63) / 64, 256, 0, stream>>>(R1h, wt1b, bnp1b, nbrT, R2h, CAP1C);

    // 7) BEV head 1 (reads R2h) -> out channels [64,128)
    hipMemsetAsync(v2r1, 0xFF, (size_t)352000 * 4, stream);
    build_vox<<<(CAP1C + 255) / 256, 256, 0, stream>>>(coords1, v2r1, CAP1C, Z1D, Y1D, X1D);
    transpose_ct1<<<320, 256, 0, stream>>>(ct1w, ct1T);
    bev1_att<<<YD * 44, 256, 0, stream>>>(R2h, ct1T, ct1b, bnt1, v2r1, out + (size_t)64 * HWOUT);
}

// Round 5
// 1892.533 us; speedup vs baseline: 5.7521x; 1.5274x over previous
//
#include <hip/hip_runtime.h>
#include <hip/hip_bf16.h>
#include <hip/hip_fp16.h>

// Problem constants
#define N_PTS_IN   20000
#define CAP0C      540000
#define CAP1C      352000
#define ZD 10
#define YD 200
#define XD 704
#define Z1D 5
#define Y1D 100
#define X1D 352
#define HWOUT (YD*XD)   // 140800

typedef _Float16 f16x8 __attribute__((ext_vector_type(8)));
typedef float    f32x4 __attribute__((ext_vector_type(4)));

// ---------------------------------------------------------------------------
// f_in = sp_feats @ w_in   (20000x64 @ 64x32), f16 output rows
__global__ __launch_bounds__(256) void gemm_in(const float* __restrict__ sp,
                                               const float* __restrict__ w,
                                               __half* __restrict__ fout) {
    int tid = blockIdx.x * 256 + threadIdx.x;
    int row = tid >> 3;
    int c4  = (tid & 7) * 4;
    if (row >= N_PTS_IN) return;
    float4 acc = {0.f, 0.f, 0.f, 0.f};
    const float* sr = sp + (size_t)row * 64;
#pragma unroll
    for (int ci = 0; ci < 64; ci += 4) {
        float4 fv = *(const float4*)(sr + ci);
        const float* wp = w + ci * 32 + c4;
        float4 w0 = *(const float4*)(wp);
        float4 w1 = *(const float4*)(wp + 32);
        float4 w2 = *(const float4*)(wp + 64);
        float4 w3 = *(const float4*)(wp + 96);
        acc.x += fv.x*w0.x + fv.y*w1.x + fv.z*w2.x + fv.w*w3.x;
        acc.y += fv.x*w0.y + fv.y*w1.y + fv.z*w2.y + fv.w*w3.y;
        acc.z += fv.x*w0.z + fv.y*w1.z + fv.z*w2.z + fv.w*w3.z;
        acc.w += fv.x*w0.w + fv.y*w1.w + fv.z*w2.w + fv.w*w3.w;
    }
    __half* fo = fout + (size_t)row * 32 + c4;
    fo[0] = __float2half(acc.x);
    fo[1] = __float2half(acc.y);
    fo[2] = __float2half(acc.z);
    fo[3] = __float2half(acc.w);
}

// ---------------------------------------------------------------------------
// Weight convert+transpose: src f32 [27][CIN][COUT] -> dst f16 [27][COUT][CIN]
__global__ __launch_bounds__(256) void cvt_w(const float* __restrict__ src,
                                             __half* __restrict__ dst,
                                             int CIN, int COUT) {
    int i = blockIdx.x * 256 + threadIdx.x;
    if (i >= 27 * CIN * COUT) return;
    int ci = i % CIN;
    int t  = i / CIN;
    int co = t % COUT;
    int k  = t / COUT;
    dst[i] = __float2half(src[((size_t)k * CIN + ci) * COUT + co]);
}

// ct0_w f32 [320][64] (ci=c*10+z) -> f16 [co][zc=z*32+c]
__global__ __launch_bounds__(256) void cvt_ct0(const float* __restrict__ src,
                                               __half* __restrict__ dst) {
    int i = blockIdx.x * 256 + threadIdx.x;
    if (i >= 64 * 320) return;
    int zc = i % 320, co = i / 320;
    int z = zc >> 5, c = zc & 31;
    dst[i] = __float2half(src[(c * 10 + z) * 64 + co]);
}

// ct1_w f32 [320][64][2][2] (ci=c*5+z) -> f16 [kq][co][zc=z*64+c]
__global__ __launch_bounds__(256) void cvt_ct1(const float* __restrict__ src,
                                               __half* __restrict__ dst) {
    int i = blockIdx.x * 256 + threadIdx.x;
    if (i >= 4 * 64 * 320) return;
    int zc = i % 320;
    int t  = i / 320;
    int co = t & 63;
    int kq = t >> 6;
    int z = zc >> 6, c = zc & 63;
    dst[i] = __float2half(src[((c * 5 + z) * 64 + co) * 4 + kq]);
}

// ---------------------------------------------------------------------------
// Rulebook inversion, TRANSPOSED: nbrT[k*cap + s] = g
__global__ __launch_bounds__(256) void build_nbr(const int* __restrict__ g,
                                                 const int* __restrict__ s,
                                                 int* __restrict__ nbrT,
                                                 int P, int cap) {
    int i = blockIdx.x * 256 + threadIdx.x;
    if (i >= 27 * P) return;
    int k = i / P, p = i - k * P;
    int sv = s[(size_t)k * P + p];
    if (sv >= cap) return;              // dummy pair
    nbrT[(size_t)k * cap + sv] = g[(size_t)k * P + p];
}

// voxel -> sparse-row index (pad coords have z == Zdim, dropped like JAX OOB)
__global__ __launch_bounds__(256) void build_vox(const int* __restrict__ coords,
                                                 int* __restrict__ v2r,
                                                 int cap, int Zdim, int Ydim, int Xdim) {
    int r = blockIdx.x * 256 + threadIdx.x;
    if (r >= cap) return;
    int b = coords[4*r], z = coords[4*r+1], y = coords[4*r+2], x = coords[4*r+3];
    if (z >= Zdim) return;
    v2r[(((size_t)b * Zdim + z) * Ydim + y) * Xdim + x] = r;
}

// ---------------------------------------------------------------------------
// Implicit-GEMM sparse conv via f16 MFMA 16x16x32, + BN + ReLU.
template <int CIN, int COUT>
__global__ __launch_bounds__(256) void spconv_mfma(const __half* __restrict__ f,
                                                   const __half* __restrict__ wt,
                                                   const float* __restrict__ bnp,
                                                   const int* __restrict__ nbrT,
                                                   __half* __restrict__ fout,
                                                   int ncap) {
    constexpr int AST = CIN + 8;                 // LDS A row stride (halves)
    constexpr int ABYTES = 64 * AST * 2;
    constexpr int OBYTES = 64 * COUT * 2;
    constexpr int LDSB = (ABYTES > OBYTES) ? ABYTES : OBYTES;
    constexpr int NT = COUT / 16;
    constexpr int KT = CIN / 32;
    __shared__ __align__(16) char smem[LDSB];
    __half* Al = (__half*)smem;

    int tid = threadIdx.x;
    int m0 = blockIdx.x * 64;
    int wv = tid >> 6, lane = tid & 63;
    int quad = lane >> 4, l16 = lane & 15;

    int srow = tid >> 2;                 // 0..63
    int schunk = tid & 3;
    int grow = m0 + srow;
    bool rowok = grow < ncap;

    float bs[NT], bb[NT];
#pragma unroll
    for (int nt = 0; nt < NT; ++nt) {
        int co = nt * 16 + l16;
        float g = bnp[co], b = bnp[COUT + co];
        float m = bnp[2*COUT + co], v = bnp[3*COUT + co];
        float s = g * rsqrtf(v + 1e-5f);
        bs[nt] = s;
        bb[nt] = b - m * s;
    }

    f32x4 acc[NT] = {};

#pragma unroll 1
    for (int k = 0; k < 27; ++k) {
        int gi = rowok ? nbrT[(size_t)k * ncap + grow] : -1;
        if (!__syncthreads_or(gi >= 0)) continue;
#pragma unroll
        for (int it = 0; it < CIN / 32; ++it) {
            int ch = schunk + it * 4;            // 8-half chunks
            uint4 v4 = {0u, 0u, 0u, 0u};
            if (gi >= 0) v4 = *(const uint4*)(f + (size_t)gi * CIN + ch * 8);
            *(uint4*)(Al + srow * AST + ch * 8) = v4;
        }
        __syncthreads();
        const __half* wk = wt + (size_t)k * COUT * CIN;
#pragma unroll
        for (int kt = 0; kt < KT; ++kt) {
            f16x8 a = *(const f16x8*)(Al + (wv * 16 + l16) * AST + kt * 32 + quad * 8);
#pragma unroll
            for (int nt = 0; nt < NT; ++nt) {
                f16x8 b = *(const f16x8*)(wk + (size_t)(nt * 16 + l16) * CIN + kt * 32 + quad * 8);
                acc[nt] = __builtin_amdgcn_mfma_f32_16x16x32_f16(a, b, acc[nt], 0, 0, 0);
            }
        }
    }

    __syncthreads();
    __half* Ol = (__half*)smem;
#pragma unroll
    for (int nt = 0; nt < NT; ++nt) {
#pragma unroll
        for (int r = 0; r < 4; ++r) {
            int m = wv * 16 + quad * 4 + r;
            float v = fmaxf(acc[nt][r] * bs[nt] + bb[nt], 0.f);
            Ol[m * COUT + nt * 16 + l16] = __float2half(v);
        }
    }
    __syncthreads();
#pragma unroll
    for (int it = 0; it < COUT / 32; ++it) {
        int ch = schunk + it * 4;
        if (rowok)
            *(uint4*)(fout + (size_t)grow * COUT + ch * 8) =
                *(const uint4*)(Ol + srow * COUT + ch * 8);
    }
}

// ---------------------------------------------------------------------------
// BEV head 0: fused gather + GEMM [64rows x 320] @ [320 x 64] via f16 MFMA,
// + BN + ReLU + 2-agent attention + coalesced store.
// Block = (y, 32 x-pixels); A-row r = pixel*2 + agent.
__global__ __launch_bounds__(256) void bev0_mfma(const __half* __restrict__ f0,
                                                 const __half* __restrict__ wtT,  // [64][320] zc=z*32+c
                                                 const float* __restrict__ bias,
                                                 const float* __restrict__ bnp,
                                                 const int* __restrict__ v2r,
                                                 float* __restrict__ out) {
    constexpr int AST = 328;
    __shared__ __align__(16) __half Al[64 * AST];   // 41,984 B
    __shared__ float Cl[64][65];                     // wave-private rows
    __shared__ float Ot[64][33];
    int tid = threadIdx.x;
    int y = blockIdx.x / 22, x0 = (blockIdx.x % 22) * 32;
    int wv = tid >> 6, lane = tid & 63;
    int quad = lane >> 4, l16 = lane & 15;

    // stage A: 640 tasks (row, z), 64 B each; invalid voxel -> zeros
    for (int it = 0; it < 3; ++it) {
        int task = it * 256 + tid;
        if (task < 640) {
            int row = task & 63, z = task >> 6;
            int b = row & 1, p = row >> 1;
            int r = v2r[((b * ZD + z) * YD + y) * XD + x0 + p];
            uint4 v0 = {0,0,0,0}, v1 = {0,0,0,0}, v2 = {0,0,0,0}, v3 = {0,0,0,0};
            if (r >= 0) {
                const uint4* src = (const uint4*)(f0 + (size_t)r * 32);
                v0 = src[0]; v1 = src[1]; v2 = src[2]; v3 = src[3];
            }
            uint4* dst = (uint4*)(Al + row * AST + z * 32);
            dst[0] = v0; dst[1] = v1; dst[2] = v2; dst[3] = v3;
        }
    }
    __syncthreads();

    f32x4 acc[4] = {};
#pragma unroll
    for (int ks = 0; ks < 10; ++ks) {
        f16x8 a = *(const f16x8*)(Al + (wv * 16 + l16) * AST + ks * 32 + quad * 8);
#pragma unroll
        for (int nt = 0; nt < 4; ++nt) {
            f16x8 bfr = *(const f16x8*)(wtT + (size_t)(nt * 16 + l16) * 320 + ks * 32 + quad * 8);
            acc[nt] = __builtin_amdgcn_mfma_f32_16x16x32_f16(a, bfr, acc[nt], 0, 0, 0);
        }
    }
    // BN + ReLU -> Cl (wave-exclusive rows, no barrier needed)
#pragma unroll
    for (int nt = 0; nt < 4; ++nt) {
        int co = nt * 16 + l16;
        float s  = bnp[co] * rsqrtf(bnp[192 + co] + 1e-5f);
        float sh = (bias[co] - bnp[128 + co]) * s + bnp[64 + co];
#pragma unroll
        for (int r_ = 0; r_ < 4; ++r_)
            Cl[wv * 16 + quad * 4 + r_][co] = fmaxf(acc[nt][r_] * s + sh, 0.f);
    }
    // attention: wave wv owns pixels [wv*8, wv*8+8); lane = cout
#pragma unroll
    for (int pi = 0; pi < 8; ++pi) {
        int p = wv * 8 + pi;
        float x0v = Cl[2 * p][lane], x1v = Cl[2 * p + 1][lane];
        float s00 = x0v * x0v, s01 = x0v * x1v;
#pragma unroll
        for (int o = 32; o > 0; o >>= 1) {
            s00 += __shfl_xor(s00, o);
            s01 += __shfl_xor(s01, o);
        }
        float a0 = s00 * 0.125f, a1 = s01 * 0.125f;
        float mx = fmaxf(a0, a1);
        float e0 = expf(a0 - mx), e1 = expf(a1 - mx);
        float inv = 1.f / (e0 + e1);
        Ot[lane][p] = (e0 * x0v + e1 * x1v) * inv;
    }
    __syncthreads();
    // store: 64 co x 32 x, coalesced in x
#pragma unroll
    for (int i = 0; i < 8; ++i) {
        int idx = i * 256 + tid;
        int co = idx >> 5, px = idx & 31;
        out[(size_t)co * HWOUT + (size_t)y * XD + x0 + px] = Ot[co][px];
    }
}

// ---------------------------------------------------------------------------
// BEV head 1: fused gather + 4x (GEMM [64x320]@[320x64]) for the 2x2 s2 convT
// kernel positions + BN + ReLU + attention + coalesced store (64-wide x rows).
__global__ __launch_bounds__(256) void bev1_mfma(const __half* __restrict__ f1,
                                                 const __half* __restrict__ wtT,  // [4][64][320] zc=z*64+c
                                                 const float* __restrict__ bias,
                                                 const float* __restrict__ bnp,
                                                 const int* __restrict__ v2r,
                                                 float* __restrict__ out) {
    constexpr int AST = 328;
    __shared__ __align__(16) __half Al[64 * AST];
    __shared__ float Cl[64][65];
    __shared__ float Ot[64][65];
    int tid = threadIdx.x;
    int iy = blockIdx.x / 11, j0 = (blockIdx.x % 11) * 32;
    int wv = tid >> 6, lane = tid & 63;
    int quad = lane >> 4, l16 = lane & 15;

    // stage A: 640 tasks (row, z-half), 64 B each
    for (int it = 0; it < 3; ++it) {
        int task = it * 256 + tid;
        if (task < 640) {
            int row = task & 63, zh = task >> 6;   // 0..9
            int z = zh >> 1, hf = zh & 1;
            int b = row & 1, p = row >> 1;
            int r = v2r[((b * Z1D + z) * Y1D + iy) * X1D + j0 + p];
            uint4 v0 = {0,0,0,0}, v1 = {0,0,0,0}, v2 = {0,0,0,0}, v3 = {0,0,0,0};
            if (r >= 0) {
                const uint4* src = (const uint4*)(f1 + (size_t)r * 64 + hf * 32);
                v0 = src[0]; v1 = src[1]; v2 = src[2]; v3 = src[3];
            }
            uint4* dst = (uint4*)(Al + row * AST + z * 64 + hf * 32);
            dst[0] = v0; dst[1] = v1; dst[2] = v2; dst[3] = v3;
        }
    }
    __syncthreads();

#pragma unroll 1
    for (int ky = 0; ky < 2; ++ky) {
#pragma unroll 1
        for (int kx = 0; kx < 2; ++kx) {
            const __half* wk = wtT + (size_t)(ky * 2 + kx) * 64 * 320;
            f32x4 acc[4] = {};
#pragma unroll
            for (int ks = 0; ks < 10; ++ks) {
                f16x8 a = *(const f16x8*)(Al + (wv * 16 + l16) * AST + ks * 32 + quad * 8);
#pragma unroll
                for (int nt = 0; nt < 4; ++nt) {
                    f16x8 bfr = *(const f16x8*)(wk + (size_t)(nt * 16 + l16) * 320 + ks * 32 + quad * 8);
                    acc[nt] = __builtin_amdgcn_mfma_f32_16x16x32_f16(a, bfr, acc[nt], 0, 0, 0);
                }
            }
#pragma unroll
            for (int nt = 0; nt < 4; ++nt) {
                int co = nt * 16 + l16;
                float s  = bnp[co] * rsqrtf(bnp[192 + co] + 1e-5f);
                float sh = (bias[co] - bnp[128 + co]) * s + bnp[64 + co];
#pragma unroll
                for (int r_ = 0; r_ < 4; ++r_)
                    Cl[wv * 16 + quad * 4 + r_][co] = fmaxf(acc[nt][r_] * s + sh, 0.f);
            }
#pragma unroll
            for (int pi = 0; pi < 8; ++pi) {
                int p = wv * 8 + pi;
                float x0v = Cl[2 * p][lane], x1v = Cl[2 * p + 1][lane];
                float s00 = x0v * x0v, s01 = x0v * x1v;
#pragma unroll
                for (int o = 32; o > 0; o >>= 1) {
                    s00 += __shfl_xor(s00, o);
                    s01 += __shfl_xor(s01, o);
                }
                float a0 = s00 * 0.125f, a1 = s01 * 0.125f;
                float mx = fmaxf(a0, a1);
                float e0 = expf(a0 - mx), e1 = expf(a1 - mx);
                float inv = 1.f / (e0 + e1);
                Ot[lane][2 * p + kx] = (e0 * x0v + e1 * x1v) * inv;
            }
        }
        __syncthreads();
        int yo = 2 * iy + ky;
#pragma unroll
        for (int i = 0; i < 16; ++i) {
            int idx = i * 256 + tid;
            int co = idx >> 6, xx = idx & 63;
            out[(size_t)co * HWOUT + (size_t)yo * XD + 2 * j0 + xx] = Ot[co][xx];
        }
        __syncthreads();
    }
}

// ---------------------------------------------------------------------------
extern "C" void kernel_launch(void* const* d_in, const int* in_sizes, int n_in,
                              void* d_out, int out_size, void* d_ws, size_t ws_size,
                              hipStream_t stream) {
    const float* sp    = (const float*)d_in[0];
    const float* w_in  = (const float*)d_in[1];
    const float* w0    = (const float*)d_in[2];
    const float* bnp0  = (const float*)d_in[3];
    const float* w0a   = (const float*)d_in[4];
    const float* bnp0a = (const float*)d_in[5];
    const float* w0b   = (const float*)d_in[6];
    const float* bnp0b = (const float*)d_in[7];
    const float* w1    = (const float*)d_in[8];
    const float* bnp1  = (const float*)d_in[9];
    const float* w1a   = (const float*)d_in[10];
    const float* bnp1a = (const float*)d_in[11];
    const float* w1b   = (const float*)d_in[12];
    const float* bnp1b = (const float*)d_in[13];
    const float* ct0w  = (const float*)d_in[14];
    const float* ct0b  = (const float*)d_in[15];
    const float* bnt0  = (const float*)d_in[16];
    const float* ct1w  = (const float*)d_in[17];
    const float* ct1b  = (const float*)d_in[18];
    const float* bnt1  = (const float*)d_in[19];
    const int* coords0 = (const int*)d_in[20];
    const int* coords1 = (const int*)d_in[21];
    const int* g0 = (const int*)d_in[22];
    const int* s0 = (const int*)d_in[23];
    const int* ga = (const int*)d_in[24];
    const int* sa = (const int*)d_in[25];
    const int* g1 = (const int*)d_in[26];
    const int* s1 = (const int*)d_in[27];
    const int* gb = (const int*)d_in[28];
    const int* sb = (const int*)d_in[29];
    float* out = (float*)d_out;

    // -------- workspace carve --------
    __half* fInH = (__half*)d_ws;
    __half* R1h  = fInH + 640000;
    __half* R2h  = R1h + 22528000;
    __half* wt0  = R2h + 22528000;
    __half* wt0a = wt0  + 27648;
    __half* wt0b = wt0a + 27648;
    __half* wt1  = wt0b + 27648;          // [27][64][32]
    __half* wt1a = wt1  + 55296;          // [27][64][64]
    __half* wt1b = wt1a + 110592;
    __half* wtT0 = wt1b + 110592;         // [64][320]
    __half* wtT1 = wtT0 + 20480;          // [4][64][320]
    int*   nbrT = (int*)(wtT1 + 81920);
    int*   v2r0 = nbrT;                          // 2,816,000 ints
    int*   v2r1 = nbrT + 2816000;                //   352,000 ints

    // 0) weight conversion
    cvt_w<<<(27*32*32 + 255) / 256, 256, 0, stream>>>(w0,  wt0,  32, 32);
    cvt_w<<<(27*32*32 + 255) / 256, 256, 0, stream>>>(w0a, wt0a, 32, 32);
    cvt_w<<<(27*32*32 + 255) / 256, 256, 0, stream>>>(w0b, wt0b, 32, 32);
    cvt_w<<<(27*32*64 + 255) / 256, 256, 0, stream>>>(w1,  wt1,  32, 64);
    cvt_w<<<(27*64*64 + 255) / 256, 256, 0, stream>>>(w1a, wt1a, 64, 64);
    cvt_w<<<(27*64*64 + 255) / 256, 256, 0, stream>>>(w1b, wt1b, 64, 64);
    cvt_ct0<<<(64*320 + 255) / 256, 256, 0, stream>>>(ct0w, wtT0);
    cvt_ct1<<<(4*64*320 + 255) / 256, 256, 0, stream>>>(ct1w, wtT1);

    // 1) input channel lift (f16 rows out)
    gemm_in<<<(N_PTS_IN * 8 + 255) / 256, 256, 0, stream>>>(sp, w_in, fInH);

    // 2) conv0 (stride-1 spconv, 32->32): fInH -> R1h
    hipMemsetAsync(nbrT, 0xFF, (size_t)CAP0C * 27 * 4, stream);
    build_nbr<<<(27 * N_PTS_IN + 255) / 256, 256, 0, stream>>>(g0, s0, nbrT, N_PTS_IN, CAP0C);
    spconv_mfma<32, 32><<<(CAP0C + 63) / 64, 256, 0, stream>>>(fInH, wt0, bnp0, nbrT, R1h, CAP0C);

    // 3) subm a/b (32->32), shared rulebook: R1h -> R2h -> R1h
    hipMemsetAsync(nbrT, 0xFF, (size_t)CAP0C * 27 * 4, stream);
    build_nbr<<<(27 * CAP0C + 255) / 256, 256, 0, stream>>>(ga, sa, nbrT, CAP0C, CAP0C);
    spconv_mfma<32, 32><<<(CAP0C + 63) / 64, 256, 0, stream>>>(R1h, wt0a, bnp0a, nbrT, R2h, CAP0C);
    spconv_mfma<32, 32><<<(CAP0C + 63) / 64, 256, 0, stream>>>(R2h, wt0b, bnp0b, nbrT, R1h, CAP0C);

    // 4) BEV head 0 (reads R1h) -> out channels [0,64)
    hipMemsetAsync(v2r0, 0xFF, (size_t)2816000 * 4, stream);
    build_vox<<<(CAP0C + 255) / 256, 256, 0, stream>>>(coords0, v2r0, CAP0C, ZD, YD, XD);
    bev0_mfma<<<YD * 22, 256, 0, stream>>>(R1h, wtT0, ct0b, bnt0, v2r0, out);

    // 5) conv1 (stride-2 spconv, 32->64): R1h -> R2h
    hipMemsetAsync(nbrT, 0xFF, (size_t)CAP1C * 27 * 4, stream);
    build_nbr<<<(27 * CAP0C + 255) / 256, 256, 0, stream>>>(g1, s1, nbrT, CAP0C, CAP1C);
    spconv_mfma<32, 64><<<(CAP1C + 63) / 64, 256, 0, stream>>>(R1h, wt1, bnp1, nbrT, R2h, CAP1C);

    // 6) subm 1a/1b (64->64), shared rulebook: R2h -> R1h -> R2h
    hipMemsetAsync(nbrT, 0xFF, (size_t)CAP1C * 27 * 4, stream);
    build_nbr<<<(27 * CAP1C + 255) / 256, 256, 0, stream>>>(gb, sb, nbrT, CAP1C, CAP1C);
    spconv_mfma<64, 64><<<(CAP1C + 63) / 64, 256, 0, stream>>>(R2h, wt1a, bnp1a, nbrT, R1h, CAP1C);
    spconv_mfma<64, 64><<<(CAP1C + 63) / 64, 256, 0, stream>>>(R1h, wt1b, bnp1b, nbrT, R2h, CAP1C);

    // 7) BEV head 1 (reads R2h) -> out channels [64,128)
    hipMemsetAsync(v2r1, 0xFF, (size_t)352000 * 4, stream);
    build_vox<<<(CAP1C + 255) / 256, 256, 0, stream>>>(coords1, v2r1, CAP1C, Z1D, Y1D, X1D);
    bev1_mfma<<<Y1D * 11, 256, 0, stream>>>(R2h, wtT1, ct1b, bnt1, v2r1, out + (size_t)64 * HWOUT);
}